// Round 6
// baseline (1549.978 us; speedup 1.0000x reference)
//
#include <hip/hip_runtime.h>

#define NN 50000      // nodes
#define NE 800000     // edges
#define FIN 512
#define H1DIM 64
#define H2DIM 128
#define NC 10
#define NG 64
#define NRT 3125      // NN/16 row-tiles

typedef __attribute__((ext_vector_type(8))) short bf16x8;  // 8 bf16 (4 VGPRs)
typedef __attribute__((ext_vector_type(4))) float f32x4;

__device__ inline short f2bf(float f) {
  unsigned u = __float_as_uint(f);
  unsigned r = u + 0x7fffu + ((u >> 16) & 1u);  // RNE
  return (short)(r >> 16);
}
__device__ inline float bf2f(short s) {
  return __uint_as_float(((unsigned)(unsigned short)s) << 16);
}

// ---------------------------------------------------------------------------
// xbf: x (f32, row-major) -> bf16 in MFMA A-frag order:
//   xbf[((rt*16 + ks)*64 + lane)*8 + j] = bf16(x[rt*16 + (lane&15)][ks*32 + (lane>>4)*8 + j])
// one wave per (rt, ks); needs NRT*16 = 50000 waves = 12500 blocks.
// ---------------------------------------------------------------------------
__global__ __launch_bounds__(256) void xbf_prep_kernel(
    const float* __restrict__ x, short* __restrict__ xbf) {
  int w = blockIdx.x * 4 + (threadIdx.x >> 6);   // 0..49999 = rt*16+ks
  int lane = threadIdx.x & 63;
  int rt = w >> 4;
  int ks = w & 15;
  int row = rt * 16 + (lane & 15);
  int k = ks * 32 + (lane >> 4) * 8;
  const float* p = x + (size_t)row * FIN + k;
  float4 v0 = *(const float4*)(p);
  float4 v1 = *(const float4*)(p + 4);
  bf16x8 o;
  o[0] = f2bf(v0.x); o[1] = f2bf(v0.y); o[2] = f2bf(v0.z); o[3] = f2bf(v0.w);
  o[4] = f2bf(v1.x); o[5] = f2bf(v1.y); o[6] = f2bf(v1.z); o[7] = f2bf(v1.w);
  *(bf16x8*)(xbf + ((size_t)w * 64 + lane) * 8) = o;
}

// ---------------------------------------------------------------------------
// wbtf: [w1_l | w1_r] -> bf16 B-frag order:
//   wbtf[((ni*16 + ks)*64 + lane)*8 + j] = bf16(W[ks*32+(lane>>4)*8+j][ni*16+(lane&15)])
// where W = concat cols (wl | wr).  131 KB total, L2-resident.
// ---------------------------------------------------------------------------
__global__ __launch_bounds__(256) void wbtf_prep_kernel(
    const float* __restrict__ wl, const float* __restrict__ wr,
    short* __restrict__ wbtf) {
  int w = blockIdx.x * 4 + (threadIdx.x >> 6);   // 0..127 = ni*16+ks
  int lane = threadIdx.x & 63;
  int ni = w >> 4;
  int ks = w & 15;
  int n = ni * 16 + (lane & 15);
  int k = ks * 32 + (lane >> 4) * 8;
  bf16x8 o;
#pragma unroll
  for (int j = 0; j < 8; j++) {
    float v = (n < 64) ? wl[(size_t)(k + j) * 64 + n]
                       : wr[(size_t)(k + j) * 64 + (n - 64)];
    o[j] = f2bf(v);
  }
  *(bf16x8*)(wbtf + ((size_t)w * 64 + lane) * 8) = o;
}

// ---------------------------------------------------------------------------
// GEMM1: LDS-free, barrier-free MFMA. One wave = 32 rows x 128 cols.
// Per K-step: 2 A-loads (contiguous 1KB/instr) + 8 B-loads (L2-hot) + 16 MFMA.
// Ping-pong register pipeline, fully unrolled.
// ---------------------------------------------------------------------------
__global__ __launch_bounds__(256) void gemm1_mfma_kernel(
    const short* __restrict__ xbf, const short* __restrict__ wbtf,
    short* __restrict__ xwl, float* __restrict__ xwr) {
  int w = blockIdx.x * 4 + (threadIdx.x >> 6);   // wave id, 32-row tiles
  int lane = threadIdx.x & 63;
  int rt0 = w * 2;
  int rt1 = rt0 + 1;
  if (rt0 >= NRT) return;
  bool ok1 = (rt1 < NRT);
  int rt1c = ok1 ? rt1 : rt0;

  const size_t la = (size_t)lane * 8;
  const short* pa0 = xbf + (size_t)rt0 * 8192 + la;   // + ks*512
  const short* pa1 = xbf + (size_t)rt1c * 8192 + la;
  const short* pb = wbtf + la;                        // + ni*8192 + ks*512

  const f32x4 z = {0.f, 0.f, 0.f, 0.f};
  f32x4 acc[2][8];
#pragma unroll
  for (int mi = 0; mi < 2; mi++)
#pragma unroll
    for (int ni = 0; ni < 8; ni++) acc[mi][ni] = z;

  bf16x8 A0[2], A1[2], B0[8], B1[8];
  A0[0] = *(const bf16x8*)(pa0);
  A0[1] = *(const bf16x8*)(pa1);
#pragma unroll
  for (int ni = 0; ni < 8; ni++)
    B0[ni] = *(const bf16x8*)(pb + (size_t)ni * 8192);

#pragma unroll
  for (int ks = 0; ks < 16; ks += 2) {
    // prefetch ks+1 while MFMAing ks
    if (ks + 1 < 16) {
      A1[0] = *(const bf16x8*)(pa0 + (ks + 1) * 512);
      A1[1] = *(const bf16x8*)(pa1 + (ks + 1) * 512);
#pragma unroll
      for (int ni = 0; ni < 8; ni++)
        B1[ni] = *(const bf16x8*)(pb + (size_t)ni * 8192 + (ks + 1) * 512);
    }
#pragma unroll
    for (int mi = 0; mi < 2; mi++)
#pragma unroll
      for (int ni = 0; ni < 8; ni++)
        acc[mi][ni] = __builtin_amdgcn_mfma_f32_16x16x32_bf16(
            A0[mi], B0[ni], acc[mi][ni], 0, 0, 0);
    // prefetch ks+2 while MFMAing ks+1
    if (ks + 2 < 16) {
      A0[0] = *(const bf16x8*)(pa0 + (ks + 2) * 512);
      A0[1] = *(const bf16x8*)(pa1 + (ks + 2) * 512);
#pragma unroll
      for (int ni = 0; ni < 8; ni++)
        B0[ni] = *(const bf16x8*)(pb + (size_t)ni * 8192 + (ks + 2) * 512);
    }
#pragma unroll
    for (int mi = 0; mi < 2; mi++)
#pragma unroll
      for (int ni = 0; ni < 8; ni++)
        acc[mi][ni] = __builtin_amdgcn_mfma_f32_16x16x32_bf16(
            A1[mi], B1[ni], acc[mi][ni], 0, 0, 0);
  }

  // epilogue: D col = ni*16 + (lane&15); row = rt*16 + (lane>>4)*4 + r
  int q = lane >> 4;
  int l15 = lane & 15;
#pragma unroll
  for (int mi = 0; mi < 2; mi++) {
    if (mi == 1 && !ok1) break;
    int row_base = (mi ? rt1 : rt0) * 16 + q * 4;
#pragma unroll
    for (int ni = 0; ni < 8; ni++) {
      int col = ni * 16 + l15;
      int c = col & 63;
#pragma unroll
      for (int r = 0; r < 4; r++) {
        int row = row_base + r;
        if (col < 64) xwl[(size_t)row * 64 + c] = f2bf(acc[mi][ni][r]);
        else          xwr[(size_t)row * 64 + c] = acc[mi][ni][r];
      }
    }
  }
}

// ---------------------------------------------------------------------------
// counting sort: hist -> multi-block scan -> scatter  (int4 edge reads)
// ---------------------------------------------------------------------------
__global__ __launch_bounds__(256) void hist_kernel(const int* __restrict__ dst,
                                                   int* __restrict__ cnt) {
  int i = (blockIdx.x * 256 + threadIdx.x) * 4;
  if (i < NE) {
    int4 d = *(const int4*)(dst + i);
    atomicAdd(&cnt[d.x], 1);
    atomicAdd(&cnt[d.y], 1);
    atomicAdd(&cnt[d.z], 1);
    atomicAdd(&cnt[d.w], 1);
  }
}

#define SCAN_BLOCKS 196   // ceil(50000/256)

__global__ __launch_bounds__(256) void scan1_kernel(const int* __restrict__ cnt,
                                                    int* __restrict__ excl,
                                                    int* __restrict__ bsum) {
  __shared__ int s[256];
  int t = threadIdx.x;
  int i = blockIdx.x * 256 + t;
  int v = (i < NN) ? cnt[i] : 0;
  s[t] = v;
  __syncthreads();
  for (int off = 1; off < 256; off <<= 1) {
    int u = (t >= off) ? s[t - off] : 0;
    __syncthreads();
    s[t] += u;
    __syncthreads();
  }
  if (i < NN) excl[i] = s[t] - v;
  if (t == 255) bsum[blockIdx.x] = s[255];
}

__global__ __launch_bounds__(256) void scan2_kernel(int* __restrict__ bsum) {
  __shared__ int s[256];
  int t = threadIdx.x;
  int v = (t < SCAN_BLOCKS) ? bsum[t] : 0;
  s[t] = v;
  __syncthreads();
  for (int off = 1; off < 256; off <<= 1) {
    int u = (t >= off) ? s[t - off] : 0;
    __syncthreads();
    s[t] += u;
    __syncthreads();
  }
  bsum[t] = s[t] - v;
}

// also accumulates poolCnt[g] (node count per graph)
__global__ __launch_bounds__(256) void scan3_kernel(const int* __restrict__ bsum,
                                                    const int* __restrict__ batch,
                                                    int* __restrict__ rowptr,
                                                    int* __restrict__ cursor,
                                                    float* __restrict__ poolCnt) {
  int t = threadIdx.x;
  int i = blockIdx.x * 256 + t;
  if (i < NN) {
    int p = rowptr[i] + bsum[blockIdx.x];
    rowptr[i] = p;
    cursor[i] = p;
    atomicAdd(&poolCnt[batch[i]], 1.0f);
  }
  if (i == 0) rowptr[NN] = NE;
}

__global__ __launch_bounds__(256) void scatter_kernel(
    const int* __restrict__ src, const int* __restrict__ dst,
    int* __restrict__ cursor, int* __restrict__ ssrc) {
  int i = (blockIdx.x * 256 + threadIdx.x) * 4;
  if (i < NE) {
    int4 s = *(const int4*)(src + i);
    int4 d = *(const int4*)(dst + i);
    int p0 = atomicAdd(&cursor[d.x], 1); ssrc[p0] = s.x;
    int p1 = atomicAdd(&cursor[d.y], 1); ssrc[p1] = s.y;
    int p2 = atomicAdd(&cursor[d.z], 1); ssrc[p2] = s.z;
    int p3 = atomicAdd(&cursor[d.w], 1); ssrc[p3] = s.w;
  }
}

// ---------------------------------------------------------------------------
// agg1 + h1 + poolB fused:
//   h1[i] = relu(mean_{s in N(i)} xwl[s] + b1 + xwr[i])  (bf16 out)
//   poolB[batch[i]] += h1[i]  (f32, pre-round)
// one wave per node; 8 chunk-lanes x 8 edge-slots, 16B gathers
// ---------------------------------------------------------------------------
__global__ __launch_bounds__(256) void agg1_h1_kernel(
    const int* __restrict__ rowptr, const int* __restrict__ ssrc,
    const int* __restrict__ batch, const short* __restrict__ xwl,
    const float* __restrict__ xwr, const float* __restrict__ b1,
    short* __restrict__ h1, float* __restrict__ poolB) {
  int node = blockIdx.x * 4 + (threadIdx.x >> 6);
  if (node >= NN) return;
  int lane = threadIdx.x & 63;
  int c = lane & 7;        // feature chunk (8 bf16 = 16 B)
  int r = lane >> 3;       // edge slot 0..7
  int lo = rowptr[node], hi = rowptr[node + 1];
  float acc[8];
#pragma unroll
  for (int k = 0; k < 8; k++) acc[k] = 0.f;
  for (int e = lo + r; e < hi; e += 8) {
    int s = ssrc[e];
    bf16x8 v = *(const bf16x8*)(xwl + (size_t)s * 64 + c * 8);
#pragma unroll
    for (int k = 0; k < 8; k++) acc[k] += bf2f(v[k]);
  }
#pragma unroll
  for (int k = 0; k < 8; k++) {
    acc[k] += __shfl_xor(acc[k], 8);
    acc[k] += __shfl_xor(acc[k], 16);
    acc[k] += __shfl_xor(acc[k], 32);
  }
  if (r == 0) {
    float dg = fmaxf((float)(hi - lo), 1.0f);
    const float* xr = xwr + (size_t)node * 64 + c * 8;
    int g = batch[node];
    float* pb = poolB + (size_t)g * 64 + c * 8;
    bf16x8 out;
#pragma unroll
    for (int k = 0; k < 8; k++) {
      float v = fmaxf(acc[k] / dg + b1[c * 8 + k] + xr[k], 0.f);
      out[k] = f2bf(v);
      atomicAdd(&pb[k], v);
    }
    *(bf16x8*)(h1 + (size_t)node * 64 + c * 8) = out;
  }
}

// ---------------------------------------------------------------------------
// aggpool2: poolA[batch[i]] += (1/max(deg_i,1)) * sum_{s in N(i)} h1[s]
// ---------------------------------------------------------------------------
__global__ __launch_bounds__(256) void aggpool2_kernel(
    const int* __restrict__ rowptr, const int* __restrict__ ssrc,
    const int* __restrict__ batch, const short* __restrict__ h1,
    float* __restrict__ poolA) {
  int node = blockIdx.x * 4 + (threadIdx.x >> 6);
  if (node >= NN) return;
  int lane = threadIdx.x & 63;
  int c = lane & 7;
  int r = lane >> 3;
  int lo = rowptr[node], hi = rowptr[node + 1];
  float acc[8];
#pragma unroll
  for (int k = 0; k < 8; k++) acc[k] = 0.f;
  for (int e = lo + r; e < hi; e += 8) {
    int s = ssrc[e];
    bf16x8 v = *(const bf16x8*)(h1 + (size_t)s * 64 + c * 8);
#pragma unroll
    for (int k = 0; k < 8; k++) acc[k] += bf2f(v[k]);
  }
#pragma unroll
  for (int k = 0; k < 8; k++) {
    acc[k] += __shfl_xor(acc[k], 8);
    acc[k] += __shfl_xor(acc[k], 16);
    acc[k] += __shfl_xor(acc[k], 32);
  }
  if (r == 0) {
    float rd = 1.0f / fmaxf((float)(hi - lo), 1.0f);
    int g = batch[node];
    float* pa = poolA + (size_t)g * 64 + c * 8;
#pragma unroll
    for (int k = 0; k < 8; k++) atomicAdd(&pa[k], acc[k] * rd);
  }
}

// ---------------------------------------------------------------------------
// final: pooled = (poolA/cnt)@w2l + (poolB/cnt)@w2r + b2 ; @wfc + bfc ;
// log_softmax. One block per graph.
// ---------------------------------------------------------------------------
__global__ __launch_bounds__(128) void final_kernel(
    const float* __restrict__ poolA, const float* __restrict__ poolB,
    const float* __restrict__ poolCnt, const float* __restrict__ w2l,
    const float* __restrict__ w2r, const float* __restrict__ b2,
    const float* __restrict__ wfc, const float* __restrict__ bfc,
    float* __restrict__ out) {
  int g = blockIdx.x;
  int j = threadIdx.x;
  __shared__ float sp[H2DIM];
  __shared__ float sl[NC];

  float invc = 1.0f / fmaxf(poolCnt[g], 1.0f);
  float v = b2[j];
  for (int k = 0; k < 64; k++) {
    float a = poolA[g * 64 + k] * invc;
    float b = poolB[g * 64 + k] * invc;
    v = fmaf(a, w2l[k * 128 + j], v);
    v = fmaf(b, w2r[k * 128 + j], v);
  }
  sp[j] = v;
  __syncthreads();
  if (j < NC) {
    float lg = bfc[j];
    for (int k = 0; k < H2DIM; k++) lg = fmaf(sp[k], wfc[k * NC + j], lg);
    sl[j] = lg;
  }
  __syncthreads();
  if (j < NC) {
    float m = -1e30f;
    for (int k = 0; k < NC; k++) m = fmaxf(m, sl[k]);
    float s = 0.f;
    for (int k = 0; k < NC; k++) s += expf(sl[k] - m);
    out[g * NC + j] = sl[j] - m - logf(s);
  }
}

extern "C" void kernel_launch(void* const* d_in, const int* in_sizes, int n_in,
                              void* d_out, int out_size, void* d_ws,
                              size_t ws_size, hipStream_t stream) {
  const float* x   = (const float*)d_in[0];
  const int* edge  = (const int*)d_in[1];
  const int* batch = (const int*)d_in[2];
  const float* w1l = (const float*)d_in[3];
  const float* b1l = (const float*)d_in[4];
  const float* w1r = (const float*)d_in[5];
  const float* w2l = (const float*)d_in[6];
  const float* b2l = (const float*)d_in[7];
  const float* w2r = (const float*)d_in[8];
  const float* wfc = (const float*)d_in[9];
  const float* bfc = (const float*)d_in[10];
  float* out = (float*)d_out;

  const int* src = edge;
  const int* dst = edge + NE;

  const size_t NF = (size_t)NN * 64;
  // zero region: cnt[NN] + poolA[4096] + poolB[4096] + poolCnt[64]
  int*   cnt     = (int*)d_ws;
  float* poolA   = (float*)(cnt + NN);
  float* poolB   = poolA + (size_t)NG * 64;
  float* poolCnt = poolB + (size_t)NG * 64;
  int*   cursor  = (int*)(poolCnt + NG);
  int*   rowptr  = cursor + NN;            // [NN+1] padded to 50004
  int*   ssrc    = rowptr + 50004;
  int*   bsum    = ssrc + NE;              // [256]
  short* xbf     = (short*)(bsum + 256);   // bf16 frag-major [NN][512]
  short* xwl     = xbf + (size_t)NN * 512; // bf16 [NN][64]
  short* h1s     = xwl + NF;               // bf16 [NN][64]
  short* wbtf    = h1s + NF;               // bf16 frag-major [128][512]
  float* xwr     = (float*)(wbtf + 65536); // f32  [NN][64]

  hipMemsetAsync(cnt, 0, (NN + 2 * NG * 64 + NG) * sizeof(int), stream);

  hist_kernel<<<(NE / 4 + 255) / 256, 256, 0, stream>>>(dst, cnt);
  scan1_kernel<<<SCAN_BLOCKS, 256, 0, stream>>>(cnt, rowptr, bsum);
  scan2_kernel<<<1, 256, 0, stream>>>(bsum);
  scan3_kernel<<<SCAN_BLOCKS, 256, 0, stream>>>(bsum, batch, rowptr, cursor, poolCnt);
  scatter_kernel<<<(NE / 4 + 255) / 256, 256, 0, stream>>>(src, dst, cursor, ssrc);

  xbf_prep_kernel<<<(NRT * 16) / 4, 256, 0, stream>>>(x, xbf);   // 12500 blocks
  wbtf_prep_kernel<<<32, 256, 0, stream>>>(w1l, w1r, wbtf);
  gemm1_mfma_kernel<<<(NRT / 2 + 4) / 4, 256, 0, stream>>>(xbf, wbtf, xwl, xwr);

  agg1_h1_kernel<<<(NN + 3) / 4, 256, 0, stream>>>(rowptr, ssrc, batch, xwl, xwr, b1l, h1s, poolB);
  aggpool2_kernel<<<(NN + 3) / 4, 256, 0, stream>>>(rowptr, ssrc, batch, h1s, poolA);
  final_kernel<<<NG, 128, 0, stream>>>(poolA, poolB, poolCnt, w2l, w2r, b2l, wfc, bfc, out);
}

// Round 7
// 366.488 us; speedup vs baseline: 4.2293x; 4.2293x over previous
//
#include <hip/hip_runtime.h>

#define NN 50000      // nodes
#define NE 800000     // edges
#define FIN 512
#define H1DIM 64
#define H2DIM 128
#define NC 10
#define NG 64
#define NRT 3125      // NN/16 row-tiles

typedef __attribute__((ext_vector_type(8))) short bf16x8;  // 8 bf16 (4 VGPRs)
typedef __attribute__((ext_vector_type(4))) float f32x4;

__device__ inline short f2bf(float f) {
  unsigned u = __float_as_uint(f);
  unsigned r = u + 0x7fffu + ((u >> 16) & 1u);  // RNE
  return (short)(r >> 16);
}
__device__ inline float bf2f(short s) {
  return __uint_as_float(((unsigned)(unsigned short)s) << 16);
}

// ---------------------------------------------------------------------------
// xbf: x (f32, row-major) -> bf16 in MFMA A-frag order.
// one wave per (rt, ks); NRT*16 = 50000 waves = 12500 blocks.
// ---------------------------------------------------------------------------
__global__ __launch_bounds__(256) void xbf_prep_kernel(
    const float* __restrict__ x, short* __restrict__ xbf) {
  int w = blockIdx.x * 4 + (threadIdx.x >> 6);   // 0..49999 = rt*16+ks
  int lane = threadIdx.x & 63;
  int rt = w >> 4;
  int ks = w & 15;
  int row = rt * 16 + (lane & 15);
  int k = ks * 32 + (lane >> 4) * 8;
  const float* p = x + (size_t)row * FIN + k;
  float4 v0 = *(const float4*)(p);
  float4 v1 = *(const float4*)(p + 4);
  bf16x8 o;
  o[0] = f2bf(v0.x); o[1] = f2bf(v0.y); o[2] = f2bf(v0.z); o[3] = f2bf(v0.w);
  o[4] = f2bf(v1.x); o[5] = f2bf(v1.y); o[6] = f2bf(v1.z); o[7] = f2bf(v1.w);
  *(bf16x8*)(xbf + ((size_t)w * 64 + lane) * 8) = o;
}

// ---------------------------------------------------------------------------
// wbtf: [w1_l | w1_r] -> bf16 B-frag order.  131 KB, L2-resident.
// ---------------------------------------------------------------------------
__global__ __launch_bounds__(256) void wbtf_prep_kernel(
    const float* __restrict__ wl, const float* __restrict__ wr,
    short* __restrict__ wbtf) {
  int w = blockIdx.x * 4 + (threadIdx.x >> 6);   // 0..127 = ni*16+ks
  int lane = threadIdx.x & 63;
  int ni = w >> 4;
  int ks = w & 15;
  int n = ni * 16 + (lane & 15);
  int k = ks * 32 + (lane >> 4) * 8;
  bf16x8 o;
#pragma unroll
  for (int j = 0; j < 8; j++) {
    float v = (n < 64) ? wl[(size_t)(k + j) * 64 + n]
                       : wr[(size_t)(k + j) * 64 + (n - 64)];
    o[j] = f2bf(v);
  }
  *(bf16x8*)(wbtf + ((size_t)w * 64 + lane) * 8) = o;
}

// ---------------------------------------------------------------------------
// GEMM1: LDS-free, barrier-free MFMA. One wave = 32 rows x 128 cols.
// ---------------------------------------------------------------------------
__global__ __launch_bounds__(256) void gemm1_mfma_kernel(
    const short* __restrict__ xbf, const short* __restrict__ wbtf,
    short* __restrict__ xwl, float* __restrict__ xwr) {
  int w = blockIdx.x * 4 + (threadIdx.x >> 6);   // wave id, 32-row tiles
  int lane = threadIdx.x & 63;
  int rt0 = w * 2;
  int rt1 = rt0 + 1;
  if (rt0 >= NRT) return;
  bool ok1 = (rt1 < NRT);
  int rt1c = ok1 ? rt1 : rt0;

  const size_t la = (size_t)lane * 8;
  const short* pa0 = xbf + (size_t)rt0 * 8192 + la;   // + ks*512
  const short* pa1 = xbf + (size_t)rt1c * 8192 + la;
  const short* pb = wbtf + la;                        // + ni*8192 + ks*512

  const f32x4 z = {0.f, 0.f, 0.f, 0.f};
  f32x4 acc[2][8];
#pragma unroll
  for (int mi = 0; mi < 2; mi++)
#pragma unroll
    for (int ni = 0; ni < 8; ni++) acc[mi][ni] = z;

  bf16x8 A0[2], A1[2], B0[8], B1[8];
  A0[0] = *(const bf16x8*)(pa0);
  A0[1] = *(const bf16x8*)(pa1);
#pragma unroll
  for (int ni = 0; ni < 8; ni++)
    B0[ni] = *(const bf16x8*)(pb + (size_t)ni * 8192);

#pragma unroll
  for (int ks = 0; ks < 16; ks += 2) {
    if (ks + 1 < 16) {
      A1[0] = *(const bf16x8*)(pa0 + (ks + 1) * 512);
      A1[1] = *(const bf16x8*)(pa1 + (ks + 1) * 512);
#pragma unroll
      for (int ni = 0; ni < 8; ni++)
        B1[ni] = *(const bf16x8*)(pb + (size_t)ni * 8192 + (ks + 1) * 512);
    }
#pragma unroll
    for (int mi = 0; mi < 2; mi++)
#pragma unroll
      for (int ni = 0; ni < 8; ni++)
        acc[mi][ni] = __builtin_amdgcn_mfma_f32_16x16x32_bf16(
            A0[mi], B0[ni], acc[mi][ni], 0, 0, 0);
    if (ks + 2 < 16) {
      A0[0] = *(const bf16x8*)(pa0 + (ks + 2) * 512);
      A0[1] = *(const bf16x8*)(pa1 + (ks + 2) * 512);
#pragma unroll
      for (int ni = 0; ni < 8; ni++)
        B0[ni] = *(const bf16x8*)(pb + (size_t)ni * 8192 + (ks + 2) * 512);
    }
#pragma unroll
    for (int mi = 0; mi < 2; mi++)
#pragma unroll
      for (int ni = 0; ni < 8; ni++)
        acc[mi][ni] = __builtin_amdgcn_mfma_f32_16x16x32_bf16(
            A1[mi], B1[ni], acc[mi][ni], 0, 0, 0);
  }

  // epilogue: D col = ni*16 + (lane&15); row = rt*16 + (lane>>4)*4 + r
  int q = lane >> 4;
  int l15 = lane & 15;
#pragma unroll
  for (int mi = 0; mi < 2; mi++) {
    if (mi == 1 && !ok1) break;
    int row_base = (mi ? rt1 : rt0) * 16 + q * 4;
#pragma unroll
    for (int ni = 0; ni < 8; ni++) {
      int col = ni * 16 + l15;
      int c = col & 63;
#pragma unroll
      for (int r = 0; r < 4; r++) {
        int row = row_base + r;
        if (col < 64) xwl[(size_t)row * 64 + c] = f2bf(acc[mi][ni][r]);
        else          xwr[(size_t)row * 64 + c] = acc[mi][ni][r];
      }
    }
  }
}

// ---------------------------------------------------------------------------
// counting sort: hist -> multi-block scan -> scatter  (int4 edge reads)
// ---------------------------------------------------------------------------
__global__ __launch_bounds__(256) void hist_kernel(const int* __restrict__ dst,
                                                   int* __restrict__ cnt) {
  int i = (blockIdx.x * 256 + threadIdx.x) * 4;
  if (i < NE) {
    int4 d = *(const int4*)(dst + i);
    atomicAdd(&cnt[d.x], 1);
    atomicAdd(&cnt[d.y], 1);
    atomicAdd(&cnt[d.z], 1);
    atomicAdd(&cnt[d.w], 1);
  }
}

#define SCAN_BLOCKS 196   // ceil(50000/256)

__global__ __launch_bounds__(256) void scan1_kernel(const int* __restrict__ cnt,
                                                    int* __restrict__ excl,
                                                    int* __restrict__ bsum) {
  __shared__ int s[256];
  int t = threadIdx.x;
  int i = blockIdx.x * 256 + t;
  int v = (i < NN) ? cnt[i] : 0;
  s[t] = v;
  __syncthreads();
  for (int off = 1; off < 256; off <<= 1) {
    int u = (t >= off) ? s[t - off] : 0;
    __syncthreads();
    s[t] += u;
    __syncthreads();
  }
  if (i < NN) excl[i] = s[t] - v;
  if (t == 255) bsum[blockIdx.x] = s[255];
}

__global__ __launch_bounds__(256) void scan2_kernel(int* __restrict__ bsum) {
  __shared__ int s[256];
  int t = threadIdx.x;
  int v = (t < SCAN_BLOCKS) ? bsum[t] : 0;
  s[t] = v;
  __syncthreads();
  for (int off = 1; off < 256; off <<= 1) {
    int u = (t >= off) ? s[t - off] : 0;
    __syncthreads();
    s[t] += u;
    __syncthreads();
  }
  bsum[t] = s[t] - v;
}

__global__ __launch_bounds__(256) void scan3_kernel(const int* __restrict__ bsum,
                                                    int* __restrict__ rowptr,
                                                    int* __restrict__ cursor) {
  int t = threadIdx.x;
  int i = blockIdx.x * 256 + t;
  if (i < NN) {
    int p = rowptr[i] + bsum[blockIdx.x];
    rowptr[i] = p;
    cursor[i] = p;
  }
  if (i == 0) rowptr[NN] = NE;
}

__global__ __launch_bounds__(256) void scatter_kernel(
    const int* __restrict__ src, const int* __restrict__ dst,
    int* __restrict__ cursor, int* __restrict__ ssrc) {
  int i = (blockIdx.x * 256 + threadIdx.x) * 4;
  if (i < NE) {
    int4 s = *(const int4*)(src + i);
    int4 d = *(const int4*)(dst + i);
    int p0 = atomicAdd(&cursor[d.x], 1); ssrc[p0] = s.x;
    int p1 = atomicAdd(&cursor[d.y], 1); ssrc[p1] = s.y;
    int p2 = atomicAdd(&cursor[d.z], 1); ssrc[p2] = s.z;
    int p3 = atomicAdd(&cursor[d.w], 1); ssrc[p3] = s.w;
  }
}

// ---------------------------------------------------------------------------
// agg1 + h1: h1[i] = relu(mean_{s in N(i)} xwl[s] + b1 + xwr[i])  (bf16 out)
// one wave per node; 8 chunk-lanes x 8 edge-slots, 16B gathers
// ---------------------------------------------------------------------------
__global__ __launch_bounds__(256) void agg1_h1_kernel(
    const int* __restrict__ rowptr, const int* __restrict__ ssrc,
    const short* __restrict__ xwl, const float* __restrict__ xwr,
    const float* __restrict__ b1, short* __restrict__ h1) {
  int node = blockIdx.x * 4 + (threadIdx.x >> 6);
  if (node >= NN) return;
  int lane = threadIdx.x & 63;
  int c = lane & 7;        // feature chunk (8 bf16 = 16 B)
  int r = lane >> 3;       // edge slot 0..7
  int lo = rowptr[node], hi = rowptr[node + 1];
  float acc[8];
#pragma unroll
  for (int k = 0; k < 8; k++) acc[k] = 0.f;
  for (int e = lo + r; e < hi; e += 8) {
    int s = ssrc[e];
    bf16x8 v = *(const bf16x8*)(xwl + (size_t)s * 64 + c * 8);
#pragma unroll
    for (int k = 0; k < 8; k++) acc[k] += bf2f(v[k]);
  }
#pragma unroll
  for (int k = 0; k < 8; k++) {
    acc[k] += __shfl_xor(acc[k], 8);
    acc[k] += __shfl_xor(acc[k], 16);
    acc[k] += __shfl_xor(acc[k], 32);
  }
  if (r == 0) {
    float dg = fmaxf((float)(hi - lo), 1.0f);
    const float* xr = xwr + (size_t)node * 64 + c * 8;
    bf16x8 out;
#pragma unroll
    for (int k = 0; k < 8; k++) {
      float v = fmaxf(acc[k] / dg + b1[c * 8 + k] + xr[k], 0.f);
      out[k] = f2bf(v);
    }
    *(bf16x8*)(h1 + (size_t)node * 64 + c * 8) = out;
  }
}

// ---------------------------------------------------------------------------
// agg2: agg2[i] = sum_{s in N(i)} h1[s]   (f32 out, per-node — NO atomics)
// ---------------------------------------------------------------------------
__global__ __launch_bounds__(256) void agg2_kernel(
    const int* __restrict__ rowptr, const int* __restrict__ ssrc,
    const short* __restrict__ h1, float* __restrict__ agg2) {
  int node = blockIdx.x * 4 + (threadIdx.x >> 6);
  if (node >= NN) return;
  int lane = threadIdx.x & 63;
  int c = lane & 7;
  int r = lane >> 3;
  int lo = rowptr[node], hi = rowptr[node + 1];
  float acc[8];
#pragma unroll
  for (int k = 0; k < 8; k++) acc[k] = 0.f;
  for (int e = lo + r; e < hi; e += 8) {
    int s = ssrc[e];
    bf16x8 v = *(const bf16x8*)(h1 + (size_t)s * 64 + c * 8);
#pragma unroll
    for (int k = 0; k < 8; k++) acc[k] += bf2f(v[k]);
  }
#pragma unroll
  for (int k = 0; k < 8; k++) {
    acc[k] += __shfl_xor(acc[k], 8);
    acc[k] += __shfl_xor(acc[k], 16);
    acc[k] += __shfl_xor(acc[k], 32);
  }
  if (r == 0) {
    float* p = agg2 + (size_t)node * 64 + c * 8;
    f32x4 lo4 = {acc[0], acc[1], acc[2], acc[3]};
    f32x4 hi4 = {acc[4], acc[5], acc[6], acc[7]};
    *(f32x4*)(p) = lo4;
    *(f32x4*)(p + 4) = hi4;
  }
}

// ---------------------------------------------------------------------------
// pool phase1: run-length accumulate (batch sorted) + sparse atomic flush
// (~few thousand atomics total — NOT per-node)
// ---------------------------------------------------------------------------
__global__ __launch_bounds__(256) void pool1_kernel(
    const int* __restrict__ batch, const float* __restrict__ agg2,
    const short* __restrict__ h1, const int* __restrict__ rowptr,
    float* __restrict__ poolA, float* __restrict__ poolB,
    float* __restrict__ poolCnt) {
  int t = threadIdx.x;
  int c = t & 15;
  int s = t >> 4;
  int n0 = blockIdx.x * 256 + s * 16;
  int n1 = n0 + 16;
  if (n1 > NN) n1 = NN;

  f32x4 aA = {0.f, 0.f, 0.f, 0.f};
  f32x4 aB = {0.f, 0.f, 0.f, 0.f};
  int cur_g = -1;
  float run = 0.f;
  for (int n = n0; n < n1; n++) {
    int g = batch[n];
    if (g != cur_g) {
      if (cur_g >= 0) {
        float* pa = poolA + (size_t)cur_g * 64 + c * 4;
        float* pb = poolB + (size_t)cur_g * 64 + c * 4;
#pragma unroll
        for (int k = 0; k < 4; k++) {
          atomicAdd(&pa[k], aA[k]);
          atomicAdd(&pb[k], aB[k]);
        }
        if (c == 0) atomicAdd(&poolCnt[cur_g], run);
      }
      cur_g = g;
      aA = (f32x4){0.f, 0.f, 0.f, 0.f};
      aB = (f32x4){0.f, 0.f, 0.f, 0.f};
      run = 0.f;
    }
    float rd = 1.0f / fmaxf((float)(rowptr[n + 1] - rowptr[n]), 1.0f);
    f32x4 a2 = *(const f32x4*)(agg2 + (size_t)n * 64 + c * 4);
    const short* hp = h1 + (size_t)n * 64 + c * 4;
#pragma unroll
    for (int k = 0; k < 4; k++) {
      aA[k] = fmaf(a2[k], rd, aA[k]);
      aB[k] += bf2f(hp[k]);
    }
    run += 1.f;
  }
  if (cur_g >= 0) {
    float* pa = poolA + (size_t)cur_g * 64 + c * 4;
    float* pb = poolB + (size_t)cur_g * 64 + c * 4;
#pragma unroll
    for (int k = 0; k < 4; k++) {
      atomicAdd(&pa[k], aA[k]);
      atomicAdd(&pb[k], aB[k]);
    }
    if (c == 0) atomicAdd(&poolCnt[cur_g], run);
  }
}

// ---------------------------------------------------------------------------
// final: pooled = (poolA/cnt)@w2l + (poolB/cnt)@w2r + b2 ; @wfc + bfc ;
// log_softmax. One block per graph.
// ---------------------------------------------------------------------------
__global__ __launch_bounds__(128) void final_kernel(
    const float* __restrict__ poolA, const float* __restrict__ poolB,
    const float* __restrict__ poolCnt, const float* __restrict__ w2l,
    const float* __restrict__ w2r, const float* __restrict__ b2,
    const float* __restrict__ wfc, const float* __restrict__ bfc,
    float* __restrict__ out) {
  int g = blockIdx.x;
  int j = threadIdx.x;
  __shared__ float sp[H2DIM];
  __shared__ float sl[NC];

  float invc = 1.0f / fmaxf(poolCnt[g], 1.0f);
  float v = b2[j];
  for (int k = 0; k < 64; k++) {
    float a = poolA[g * 64 + k] * invc;
    float b = poolB[g * 64 + k] * invc;
    v = fmaf(a, w2l[k * 128 + j], v);
    v = fmaf(b, w2r[k * 128 + j], v);
  }
  sp[j] = v;
  __syncthreads();
  if (j < NC) {
    float lg = bfc[j];
    for (int k = 0; k < H2DIM; k++) lg = fmaf(sp[k], wfc[k * NC + j], lg);
    sl[j] = lg;
  }
  __syncthreads();
  if (j < NC) {
    float m = -1e30f;
    for (int k = 0; k < NC; k++) m = fmaxf(m, sl[k]);
    float s = 0.f;
    for (int k = 0; k < NC; k++) s += expf(sl[k] - m);
    out[g * NC + j] = sl[j] - m - logf(s);
  }
}

extern "C" void kernel_launch(void* const* d_in, const int* in_sizes, int n_in,
                              void* d_out, int out_size, void* d_ws,
                              size_t ws_size, hipStream_t stream) {
  const float* x   = (const float*)d_in[0];
  const int* edge  = (const int*)d_in[1];
  const int* batch = (const int*)d_in[2];
  const float* w1l = (const float*)d_in[3];
  const float* b1l = (const float*)d_in[4];
  const float* w1r = (const float*)d_in[5];
  const float* w2l = (const float*)d_in[6];
  const float* b2l = (const float*)d_in[7];
  const float* w2r = (const float*)d_in[8];
  const float* wfc = (const float*)d_in[9];
  const float* bfc = (const float*)d_in[10];
  float* out = (float*)d_out;

  const int* src = edge;
  const int* dst = edge + NE;

  const size_t NF = (size_t)NN * 64;
  // zero region: cnt[NN] + poolA[4096] + poolB[4096] + poolCnt[64]
  int*   cnt     = (int*)d_ws;
  float* poolA   = (float*)(cnt + NN);
  float* poolB   = poolA + (size_t)NG * 64;
  float* poolCnt = poolB + (size_t)NG * 64;
  int*   cursor  = (int*)(poolCnt + NG);
  int*   rowptr  = cursor + NN;            // [NN+1] padded to 50004
  int*   ssrc    = rowptr + 50004;
  int*   bsum    = ssrc + NE;              // [256]
  short* xbf     = (short*)(bsum + 256);   // bf16 frag-major [NN][512]
  short* xwl     = xbf + (size_t)NN * 512; // bf16 [NN][64]
  short* h1s     = xwl + NF;               // bf16 [NN][64]
  short* wbtf    = h1s + NF;               // bf16 frag-major [128][512]
  float* xwr     = (float*)(wbtf + 65536); // f32  [NN][64]
  float* agg2    = xwr + NF;               // f32  [NN][64]

  hipMemsetAsync(cnt, 0, (NN + 2 * NG * 64 + NG) * sizeof(int), stream);

  hist_kernel<<<(NE / 4 + 255) / 256, 256, 0, stream>>>(dst, cnt);
  scan1_kernel<<<SCAN_BLOCKS, 256, 0, stream>>>(cnt, rowptr, bsum);
  scan2_kernel<<<1, 256, 0, stream>>>(bsum);
  scan3_kernel<<<SCAN_BLOCKS, 256, 0, stream>>>(bsum, rowptr, cursor);
  scatter_kernel<<<(NE / 4 + 255) / 256, 256, 0, stream>>>(src, dst, cursor, ssrc);

  xbf_prep_kernel<<<(NRT * 16) / 4, 256, 0, stream>>>(x, xbf);   // 12500 blocks
  wbtf_prep_kernel<<<32, 256, 0, stream>>>(w1l, w1r, wbtf);
  gemm1_mfma_kernel<<<(NRT / 2 + 4) / 4, 256, 0, stream>>>(xbf, wbtf, xwl, xwr);

  agg1_h1_kernel<<<(NN + 3) / 4, 256, 0, stream>>>(rowptr, ssrc, xwl, xwr, b1l, h1s);
  agg2_kernel<<<(NN + 3) / 4, 256, 0, stream>>>(rowptr, ssrc, h1s, agg2);
  pool1_kernel<<<SCAN_BLOCKS, 256, 0, stream>>>(batch, agg2, h1s, rowptr, poolA, poolB, poolCnt);
  final_kernel<<<NG, 128, 0, stream>>>(poolA, poolB, poolCnt, w2l, w2r, b2l, wfc, bfc, out);
}